// Round 16
// baseline (338.924 us; speedup 1.0000x reference)
//
#include <hip/hip_runtime.h>
#include <hip/hip_fp16.h>

using f16x8 = __attribute__((ext_vector_type(8))) _Float16;
using f32x4 = __attribute__((ext_vector_type(4))) float;
using f32x2v = __attribute__((ext_vector_type(2))) float;

// ---------------- wave helpers (wave = 64 lanes on CDNA) ----------------
static __device__ __forceinline__ float wred_sum(float v) {
#pragma unroll
  for (int o = 32; o > 0; o >>= 1) v += __shfl_xor(v, o);
  return v;
}
static __device__ __forceinline__ float lrelu(float x) { return x > 0.f ? x : 0.2f * x; }

// ---------------- preprocessing ----------------
__global__ void count_rank(const int* __restrict__ dst, int* __restrict__ deg,
                           int* __restrict__ rank, int E) {
  int i = blockIdx.x * blockDim.x + threadIdx.x;
  if (i < E) rank[i] = atomicAdd(&deg[dst[i]], 1);
}

__global__ __launch_bounds__(256) void scan_part(const int* __restrict__ deg,
                                                 int* __restrict__ bsum, int n) {
  __shared__ int sd[256];
  int tid = threadIdx.x;
  int i = blockIdx.x * 256 + tid;
  sd[tid] = (i < n) ? deg[i] : 0;
  __syncthreads();
#pragma unroll
  for (int d = 128; d > 0; d >>= 1) {
    if (tid < d) sd[tid] += sd[tid + d];
    __syncthreads();
  }
  if (tid == 0) bsum[blockIdx.x] = sd[0];
}

__global__ __launch_bounds__(256) void scan_final(const int* __restrict__ deg,
                                                  const int* __restrict__ bsum,
                                                  int* __restrict__ row_start, int n, int nb) {
  __shared__ int sd[256];
  __shared__ int sbase;
  int tid = threadIdx.x;
  int b = blockIdx.x;
  int v = (tid < nb && tid < b) ? bsum[tid] : 0;
  sd[tid] = v;
  __syncthreads();
#pragma unroll
  for (int d = 128; d > 0; d >>= 1) {
    if (tid < d) sd[tid] += sd[tid + d];
    __syncthreads();
  }
  if (tid == 0) sbase = sd[0];
  __syncthreads();
  int i = b * 256 + tid;
  int dv = (i < n) ? deg[i] : 0;
  sd[tid] = dv;
  __syncthreads();
#pragma unroll
  for (int d = 1; d < 256; d <<= 1) {
    int t = (tid >= d) ? sd[tid - d] : 0;
    __syncthreads();
    sd[tid] += t;
    __syncthreads();
  }
  int incl = sd[tid];
  if (i < n) row_start[i] = sbase + incl - dv;
  if (i == n - 1) row_start[n] = sbase + incl;
}

__global__ void scatter_edges(const int* __restrict__ src, const int* __restrict__ dst,
                              const int* __restrict__ row_start, const int* __restrict__ rank,
                              int2* __restrict__ se, int E) {
  int i = blockIdx.x * blockDim.x + threadIdx.x;
  if (i < E) {
    int d = dst[i];
    int pos = row_start[d] + rank[i];
    se[pos] = make_int2(src[i], i);
  }
}

// ---------------- fused weight prep: 3 transposes + wvec in one launch ----------------
__global__ __launch_bounds__(256) void prep_weights(
    const float* __restrict__ W0, __half* __restrict__ W0t,
    const float* __restrict__ W1, __half* __restrict__ W1t,
    const float* __restrict__ W2, __half* __restrict__ W2t,
    const float* __restrict__ We0, const float* __restrict__ ae0w,
    const float* __restrict__ We1, const float* __restrict__ ae1w,
    const float* __restrict__ We2, const float* __restrict__ ae2w,
    float* __restrict__ wv) {
  int b = blockIdx.x;
  if (b >= 448) {  // wvec block
    int t = threadIdx.x;
    if (t < 144) {
      int k = t >> 4, d = t & 15;
      const float* We; const float* aev; int h; int HC;
      if (k < 4)      { We = We0; aev = ae0w; h = k;     HC = 256; }
      else if (k < 8) { We = We1; aev = ae1w; h = k - 4; HC = 256; }
      else            { We = We2; aev = ae2w; h = 0;     HC = 64; }
      float sum = 0.f;
#pragma unroll
      for (int c = 0; c < 64; ++c) sum += We[(size_t)d * HC + h * 64 + c] * aev[h * 64 + c];
      wv[k * 16 + d] = sum;
    }
    return;
  }
  const float* W; __half* Wt; int K, Nc, bx, by;
  if (b < 128)      { W = W0; Wt = W0t; K = 128; Nc = 256; bx = b & 15; by = b >> 4; }
  else if (b < 384) { int c = b - 128; W = W1; Wt = W1t; K = 256; Nc = 256; bx = c & 15; by = c >> 4; }
  else              { int c = b - 384; W = W2; Wt = W2t; K = 256; Nc = 64;  bx = c & 3;  by = c >> 2; }
  int n = bx * 16 + (threadIdx.x & 15);
  int k = by * 16 + (threadIdx.x >> 4);
  if (n < Nc && k < K) Wt[(size_t)n * K + k] = __float2half(W[(size_t)k * Nc + n]);
}

// per-edge attention coefficients, CSR-sorted order (random READ, coalesced writes)
__global__ __launch_bounds__(256) void edge_ae(const float* __restrict__ ea,
                                               const int2* __restrict__ se,
                                               const float* __restrict__ wv,
                                               float* __restrict__ ae0, float* __restrict__ ae1,
                                               float* __restrict__ ae2, int E) {
  __shared__ float swv[144];
  if (threadIdx.x < 144) swv[threadIdx.x] = wv[threadIdx.x];
  __syncthreads();
  int p = blockIdx.x * blockDim.x + threadIdx.x;
  if (p >= E) return;
  int e = se[p].y;
  const float4* er = (const float4*)(ea + (size_t)e * 16);
  float4 v0 = er[0], v1 = er[1], v2 = er[2], v3 = er[3];
  float ev[16] = {v0.x, v0.y, v0.z, v0.w, v1.x, v1.y, v1.z, v1.w,
                  v2.x, v2.y, v2.z, v2.w, v3.x, v3.y, v3.z, v3.w};
  float r[9];
#pragma unroll
  for (int k = 0; k < 9; ++k) {
    float s = 0.f;
#pragma unroll
    for (int d = 0; d < 16; ++d) s += ev[d] * swv[k * 16 + d];
    r[k] = s;
  }
  *(float4*)(ae0 + (size_t)p * 4) = make_float4(r[0], r[1], r[2], r[3]);
  *(float4*)(ae1 + (size_t)p * 4) = make_float4(r[4], r[5], r[6], r[7]);
  ae2[p] = r[8];
}

// ---------------- f16 MFMA GEMM, double-buffered reg-staged pipeline (BK=32) ----------------
// Wide grid: BN=64 (or BM=64) so ~1500 blocks saturate 256 CUs.
// asad dots are PARTIAL per wave (WN=32 = half a head) -> atomicAdd onto zeroed asb/adb.
template <int BM, int BN, bool AF32, int HS, bool XF8>
__global__ __launch_bounds__(256) void gemm_f16mfma(const void* __restrict__ Av,
                                                    const __half* __restrict__ Bt,
                                                    void* __restrict__ Cv,
                                                    const float* __restrict__ as_w,
                                                    const float* __restrict__ ad_w,
                                                    float* __restrict__ asb,
                                                    float* __restrict__ adb,
                                                    int M, int K, int Nc) {
  constexpr int BK = 32;
  constexpr int LDT = BK + 8;  // 40 f16 = 80B row stride
  constexpr int WM = BM / 2;
  constexpr int WN = BN / 2;
  constexpr int NFM = WM / 16;
  constexpr int NFN = WN / 16;
  constexpr int NCA = AF32 ? (BM / 32) : (BM / 64);  // A 16B chunks / thread
  constexpr int NCB = BN / 64;
  __shared__ __half As[2][BM][LDT];
  __shared__ __half Bs[2][BN][LDT];
  const int tid = threadIdx.x;
  const int lane = tid & 63, wave = tid >> 6;
  const int wr = wave >> 1, wc = wave & 1;
  const int bm = blockIdx.x * BM;
  const int bn = blockIdx.y * BN;
  const int r15 = lane & 15, kgrp = lane >> 4;
  f32x4 acc[NFM][NFN] = {};
  float4 sa[NCA];
  float4 sb[NCB];

  auto issue_loads = [&](int t) {
    int k0 = t * BK;
    if constexpr (AF32) {
      const float* A = (const float*)Av;
#pragma unroll
      for (int i = 0; i < NCA; ++i) {
        int chunk = tid + i * 256;
        int row = chunk >> 3, kc = (chunk & 7) * 4;
        int grow = bm + row;
        float4 v = make_float4(0, 0, 0, 0);
        if (grow < M) v = *(const float4*)(A + (size_t)grow * K + k0 + kc);
        sa[i] = v;
      }
    } else {
      const __half* A = (const __half*)Av;
#pragma unroll
      for (int i = 0; i < NCA; ++i) {
        int chunk = tid + i * 256;
        int row = chunk >> 2, kc = (chunk & 3) * 8;
        int grow = bm + row;
        float4 v = make_float4(0, 0, 0, 0);
        if (grow < M) v = *(const float4*)(A + (size_t)grow * K + k0 + kc);
        sa[i] = v;
      }
    }
#pragma unroll
    for (int i = 0; i < NCB; ++i) {
      int chunk = tid + i * 256;
      int row = chunk >> 2, kc = (chunk & 3) * 8;
      sb[i] = *(const float4*)(Bt + (size_t)(bn + row) * K + t * BK + kc);
    }
  };
  auto write_lds = [&](int buf) {
    if constexpr (AF32) {
#pragma unroll
      for (int i = 0; i < NCA; ++i) {
        int chunk = tid + i * 256;
        int row = chunk >> 3, kc = (chunk & 7) * 4;
        float4 v = sa[i];
        __half2 h01 = __floats2half2_rn(v.x, v.y);
        __half2 h23 = __floats2half2_rn(v.z, v.w);
        uint2 u;
        u.x = *(unsigned*)&h01;
        u.y = *(unsigned*)&h23;
        *(uint2*)&As[buf][row][kc] = u;
      }
    } else {
#pragma unroll
      for (int i = 0; i < NCA; ++i) {
        int chunk = tid + i * 256;
        int row = chunk >> 2, kc = (chunk & 3) * 8;
        *(float4*)&As[buf][row][kc] = sa[i];
      }
    }
#pragma unroll
    for (int i = 0; i < NCB; ++i) {
      int chunk = tid + i * 256;
      int row = chunk >> 2, kc = (chunk & 3) * 8;
      *(float4*)&Bs[buf][row][kc] = sb[i];
    }
  };
  auto compute = [&](int buf) {
    f16x8 af[NFM], bf[NFN];
#pragma unroll
    for (int mi = 0; mi < NFM; ++mi)
      af[mi] = *(const f16x8*)&As[buf][wr * WM + mi * 16 + r15][kgrp * 8];
#pragma unroll
    for (int ni = 0; ni < NFN; ++ni)
      bf[ni] = *(const f16x8*)&Bs[buf][wc * WN + ni * 16 + r15][kgrp * 8];
#pragma unroll
    for (int mi = 0; mi < NFM; ++mi)
#pragma unroll
      for (int ni = 0; ni < NFN; ++ni)
        acc[mi][ni] = __builtin_amdgcn_mfma_f32_16x16x32_f16(af[mi], bf[ni], acc[mi][ni], 0, 0, 0);
  };

  const int nt = K / BK;
  issue_loads(0);
  write_lds(0);
  __syncthreads();
  for (int t = 0; t < nt; ++t) {
    int cur = t & 1;
    if (t + 1 < nt) issue_loads(t + 1);
    compute(cur);
    if (t + 1 < nt) {
      write_lds(cur ^ 1);
      __syncthreads();
    }
  }

  float asw[NFN], adw[NFN];
#pragma unroll
  for (int ni = 0; ni < NFN; ++ni) {
    int gcol = bn + wc * WN + ni * 16 + r15;
    asw[ni] = as_w[gcol];
    adw[ni] = ad_w[gcol];
  }
  const int hidx = (bn + wc * WN) >> 6;
#pragma unroll
  for (int mi = 0; mi < NFM; ++mi) {
#pragma unroll
    for (int r = 0; r < 4; ++r) {
      int grow = bm + wr * WM + mi * 16 + kgrp * 4 + r;
      bool valid = grow < M;
      float sdot = 0.f, ddot = 0.f;
#pragma unroll
      for (int ni = 0; ni < NFN; ++ni) {
        float v = acc[mi][ni][r];
        if (valid) {
          int gcol = bn + wc * WN + ni * 16 + r15;
          if constexpr (XF8) {
            unsigned pk = (unsigned)__builtin_amdgcn_cvt_pk_fp8_f32(v, v, 0, false);
            ((unsigned char*)Cv)[(size_t)grow * Nc + gcol] = (unsigned char)(pk & 0xff);
          } else {
            ((__half*)Cv)[(size_t)grow * Nc + gcol] = __float2half(v);
          }
        }
        sdot = fmaf(v, asw[ni], sdot);
        ddot = fmaf(v, adw[ni], ddot);
      }
#pragma unroll
      for (int o = 8; o >= 1; o >>= 1) {
        sdot += __shfl_xor(sdot, o);
        ddot += __shfl_xor(ddot, o);
      }
      if (valid && r15 == 0) {
        atomicAdd(&asb[(size_t)grow * HS + (HS == 1 ? 0 : hidx)], sdot);
        atomicAdd(&adb[(size_t)grow * HS + (HS == 1 ? 0 : hidx)], ddot);
      }
    }
  }
}

// ---------------- fused segment-softmax + aggregation, heads=4 C=64, fp8 gather ----------------
// softmax WITHOUT max subtraction (shift-invariant; logits far below f32 exp overflow)
__global__ __launch_bounds__(256) void agg_heads4(
    const unsigned char* __restrict__ xp, const int2* __restrict__ se,
    const int* __restrict__ row_start, const float* __restrict__ asb,
    const float* __restrict__ adb, const float* __restrict__ ae,
    const float* __restrict__ bias, __half* __restrict__ out, int N) {
  __shared__ float sw[4][256];
  __shared__ int ssrc[4][64];  // pre-shifted row byte offsets (s << 8)
  int wave = threadIdx.x >> 6, lane = threadIdx.x & 63;
  int n = blockIdx.x * 4 + wave;
  if (n >= N) return;
  int beg = row_start[n], end = row_start[n + 1];
  int deg = end - beg;
  int hsel = lane >> 4;
  float4 adn = *(const float4*)(adb + (size_t)n * 4);
  float4 asn = *(const float4*)(asb + (size_t)n * 4);
  float invd = 1.f / fmaxf((float)deg, 1.f);
  float acc0 = 0, acc1 = 0, acc2 = 0, acc3 = 0;
  float den0 = 0, den1 = 0, den2 = 0, den3 = 0;
  float al0, al1, al2, al3, exl0, exl1, exl2, exl3;
  const int loff = lane << 2;  // 4 fp8 bytes / lane

  if (deg <= 64) {
    int j = beg + lane;
    bool act = j < end;
    int s = 0;
    float4 asv = make_float4(0, 0, 0, 0), aev = make_float4(0, 0, 0, 0);
    if (act) {
      s = se[j].x;
      asv = *(const float4*)(asb + (size_t)s * 4);
      aev = *(const float4*)(ae + (size_t)j * 4);
    }
    float ex0 = act ? __expf(lrelu(asv.x + adn.x + aev.x)) : 0.f;
    float ex1 = act ? __expf(lrelu(asv.y + adn.y + aev.y)) : 0.f;
    float ex2 = act ? __expf(lrelu(asv.z + adn.z + aev.z)) : 0.f;
    float ex3 = act ? __expf(lrelu(asv.w + adn.w + aev.w)) : 0.f;
    float aes0 = wred_sum(aev.x), aes1 = wred_sum(aev.y), aes2 = wred_sum(aev.z), aes3 = wred_sum(aev.w);
    al0 = lrelu(asn.x + adn.x + aes0 * invd);
    al1 = lrelu(asn.y + adn.y + aes1 * invd);
    al2 = lrelu(asn.z + adn.z + aes2 * invd);
    al3 = lrelu(asn.w + adn.w + aes3 * invd);
    exl0 = __expf(al0); exl1 = __expf(al1); exl2 = __expf(al2); exl3 = __expf(al3);
    den0 = wred_sum(ex0); den1 = wred_sum(ex1); den2 = wred_sum(ex2); den3 = wred_sum(ex3);
    *(float4*)&sw[wave][lane << 2] = make_float4(ex0, ex1, ex2, ex3);
    ssrc[wave][lane] = s << 8;
    asm volatile("" ::: "memory");
    int cnt = deg;
    int sj0 = ssrc[wave][0], sj1 = ssrc[wave][1], sj2 = ssrc[wave][2], sj3 = ssrc[wave][3];
    unsigned B0 = *(const unsigned*)(xp + sj0 + loff);
    unsigned B1 = *(const unsigned*)(xp + sj1 + loff);
    unsigned B2 = *(const unsigned*)(xp + sj2 + loff);
    unsigned B3 = *(const unsigned*)(xp + sj3 + loff);
    for (int t = 0; t < cnt; t += 4) {
      {
        float w = sw[wave][((t + 0) << 2) + hsel];
        f32x2v lo = __builtin_amdgcn_cvt_pk_f32_fp8((int)B0, false);
        f32x2v hi = __builtin_amdgcn_cvt_pk_f32_fp8((int)B0, true);
        acc0 = fmaf(w, lo[0], acc0); acc1 = fmaf(w, lo[1], acc1);
        acc2 = fmaf(w, hi[0], acc2); acc3 = fmaf(w, hi[1], acc3);
        int ns = ssrc[wave][(t + 4) & 63];
        B0 = *(const unsigned*)(xp + ns + loff);
      }
      {
        float w = sw[wave][((t + 1) << 2) + hsel];
        f32x2v lo = __builtin_amdgcn_cvt_pk_f32_fp8((int)B1, false);
        f32x2v hi = __builtin_amdgcn_cvt_pk_f32_fp8((int)B1, true);
        acc0 = fmaf(w, lo[0], acc0); acc1 = fmaf(w, lo[1], acc1);
        acc2 = fmaf(w, hi[0], acc2); acc3 = fmaf(w, hi[1], acc3);
        int ns = ssrc[wave][(t + 5) & 63];
        B1 = *(const unsigned*)(xp + ns + loff);
      }
      {
        float w = sw[wave][((t + 2) << 2) + hsel];
        f32x2v lo = __builtin_amdgcn_cvt_pk_f32_fp8((int)B2, false);
        f32x2v hi = __builtin_amdgcn_cvt_pk_f32_fp8((int)B2, true);
        acc0 = fmaf(w, lo[0], acc0); acc1 = fmaf(w, lo[1], acc1);
        acc2 = fmaf(w, hi[0], acc2); acc3 = fmaf(w, hi[1], acc3);
        int ns = ssrc[wave][(t + 6) & 63];
        B2 = *(const unsigned*)(xp + ns + loff);
      }
      {
        float w = sw[wave][((t + 3) << 2) + hsel];
        f32x2v lo = __builtin_amdgcn_cvt_pk_f32_fp8((int)B3, false);
        f32x2v hi = __builtin_amdgcn_cvt_pk_f32_fp8((int)B3, true);
        acc0 = fmaf(w, lo[0], acc0); acc1 = fmaf(w, lo[1], acc1);
        acc2 = fmaf(w, hi[0], acc2); acc3 = fmaf(w, hi[1], acc3);
        int ns = ssrc[wave][(t + 7) & 63];
        B3 = *(const unsigned*)(xp + ns + loff);
      }
    }
  } else {
    float aes0 = 0, aes1 = 0, aes2 = 0, aes3 = 0;
    for (int base = beg; base < end; base += 64) {
      int j = base + lane;
      if (j < end) {
        float4 aev = *(const float4*)(ae + (size_t)j * 4);
        aes0 += aev.x; aes1 += aev.y; aes2 += aev.z; aes3 += aev.w;
      }
    }
    aes0 = wred_sum(aes0); aes1 = wred_sum(aes1); aes2 = wred_sum(aes2); aes3 = wred_sum(aes3);
    al0 = lrelu(asn.x + adn.x + aes0 * invd);
    al1 = lrelu(asn.y + adn.y + aes1 * invd);
    al2 = lrelu(asn.z + adn.z + aes2 * invd);
    al3 = lrelu(asn.w + adn.w + aes3 * invd);
    exl0 = __expf(al0); exl1 = __expf(al1); exl2 = __expf(al2); exl3 = __expf(al3);
    for (int base = beg; base < end; base += 64) {
      int j = base + lane;
      float ex0 = 0, ex1 = 0, ex2 = 0, ex3 = 0;
      int s = 0;
      if (j < end) {
        s = se[j].x;
        float4 asv = *(const float4*)(asb + (size_t)s * 4);
        float4 aev = *(const float4*)(ae + (size_t)j * 4);
        ex0 = __expf(lrelu(asv.x + adn.x + aev.x));
        ex1 = __expf(lrelu(asv.y + adn.y + aev.y));
        ex2 = __expf(lrelu(asv.z + adn.z + aev.z));
        ex3 = __expf(lrelu(asv.w + adn.w + aev.w));
        den0 += ex0; den1 += ex1; den2 += ex2; den3 += ex3;
      }
      int cnt = min(64, end - base);
      for (int t = 0; t < cnt; ++t) {
        int sj = __shfl(s, t);
        float w0 = __shfl(ex0, t), w1 = __shfl(ex1, t), w2 = __shfl(ex2, t), w3 = __shfl(ex3, t);
        float w = hsel == 0 ? w0 : (hsel == 1 ? w1 : (hsel == 2 ? w2 : w3));
        unsigned u = *(const unsigned*)(xp + ((size_t)sj << 8) + loff);
        f32x2v lo = __builtin_amdgcn_cvt_pk_f32_fp8((int)u, false);
        f32x2v hi = __builtin_amdgcn_cvt_pk_f32_fp8((int)u, true);
        acc0 = fmaf(w, lo[0], acc0);
        acc1 = fmaf(w, lo[1], acc1);
        acc2 = fmaf(w, hi[0], acc2);
        acc3 = fmaf(w, hi[1], acc3);
      }
    }
    den0 = wred_sum(den0); den1 = wred_sum(den1); den2 = wred_sum(den2); den3 = wred_sum(den3);
  }

  den0 += exl0; den1 += exl1; den2 += exl2; den3 += exl3;
  float exh = hsel == 0 ? exl0 : (hsel == 1 ? exl1 : (hsel == 2 ? exl2 : exl3));
  {
    unsigned u = *(const unsigned*)(xp + ((size_t)n << 8) + loff);
    f32x2v lo = __builtin_amdgcn_cvt_pk_f32_fp8((int)u, false);
    f32x2v hi = __builtin_amdgcn_cvt_pk_f32_fp8((int)u, true);
    acc0 = fmaf(exh, lo[0], acc0);
    acc1 = fmaf(exh, lo[1], acc1);
    acc2 = fmaf(exh, hi[0], acc2);
    acc3 = fmaf(exh, hi[1], acc3);
  }
  float denh = hsel == 0 ? den0 : (hsel == 1 ? den1 : (hsel == 2 ? den2 : den3));
  float rden = 1.f / (denh + 1e-16f);
  float4 bv = *(const float4*)(bias + (lane << 2));
  __half2 o01 = __floats2half2_rn(fmaxf(acc0 * rden + bv.x, 0.f), fmaxf(acc1 * rden + bv.y, 0.f));
  __half2 o23 = __floats2half2_rn(fmaxf(acc2 * rden + bv.z, 0.f), fmaxf(acc3 * rden + bv.w, 0.f));
  uint2 u;
  u.x = *(unsigned*)&o01;
  u.y = *(unsigned*)&o23;
  *(uint2*)(out + (size_t)n * 256 + (lane << 2)) = u;
}

// ---------------- layer2 (heads=1, fp16 table) + final linear + sigmoid, fused ----------------
__global__ __launch_bounds__(256) void agg1_final(
    const __half* __restrict__ xp, const int2* __restrict__ se,
    const int* __restrict__ row_start, const float* __restrict__ asb,
    const float* __restrict__ adb, const float* __restrict__ ae,
    const float* __restrict__ b2, const float* __restrict__ lin_w,
    const float* __restrict__ lin_b, float* __restrict__ out, int N) {
  __shared__ float sw1[4][64];
  __shared__ int ssrc1[4][64];
  int wave = threadIdx.x >> 6, lane = threadIdx.x & 63;
  int n = blockIdx.x * 4 + wave;
  if (n >= N) return;
  int beg = row_start[n], end = row_start[n + 1];
  int deg = end - beg;
  float adn = adb[n], asn = asb[n];
  float invd = 1.f / fmaxf((float)deg, 1.f);
  float al, exl, acc = 0, den = 0;

  if (deg <= 64) {
    int j = beg + lane;
    bool act = j < end;
    int s = 0;
    float aev = 0, asvs = 0;
    if (act) { s = se[j].x; aev = ae[j]; asvs = asb[s]; }
    float ex = act ? __expf(lrelu(asvs + adn + aev)) : 0.f;
    float aes = wred_sum(aev);
    al = lrelu(asn + adn + aes * invd);
    exl = __expf(al);
    den = wred_sum(ex);
    sw1[wave][lane] = ex;
    ssrc1[wave][lane] = s;
    asm volatile("" ::: "memory");
    int cnt = deg;
    int sj0 = ssrc1[wave][0], sj1 = ssrc1[wave][1], sj2 = ssrc1[wave][2], sj3 = ssrc1[wave][3];
    __half H0 = xp[((size_t)sj0 << 6) + lane];
    __half H1 = xp[((size_t)sj1 << 6) + lane];
    __half H2 = xp[((size_t)sj2 << 6) + lane];
    __half H3 = xp[((size_t)sj3 << 6) + lane];
    for (int t = 0; t < cnt; t += 4) {
      {
        float w = sw1[wave][t + 0];
        acc = fmaf(w, __half2float(H0), acc);
        int ns = ssrc1[wave][(t + 4) & 63];
        H0 = xp[((size_t)ns << 6) + lane];
      }
      {
        float w = sw1[wave][t + 1];
        acc = fmaf(w, __half2float(H1), acc);
        int ns = ssrc1[wave][(t + 5) & 63];
        H1 = xp[((size_t)ns << 6) + lane];
      }
      {
        float w = sw1[wave][t + 2];
        acc = fmaf(w, __half2float(H2), acc);
        int ns = ssrc1[wave][(t + 6) & 63];
        H2 = xp[((size_t)ns << 6) + lane];
      }
      {
        float w = sw1[wave][t + 3];
        acc = fmaf(w, __half2float(H3), acc);
        int ns = ssrc1[wave][(t + 7) & 63];
        H3 = xp[((size_t)ns << 6) + lane];
      }
    }
  } else {
    float aes = 0;
    for (int base = beg; base < end; base += 64) {
      int j = base + lane;
      if (j < end) aes += ae[j];
    }
    aes = wred_sum(aes);
    al = lrelu(asn + adn + aes * invd);
    exl = __expf(al);
    for (int base = beg; base < end; base += 64) {
      int j = base + lane;
      float ex = 0;
      int s = 0;
      if (j < end) {
        s = se[j].x;
        ex = __expf(lrelu(asb[s] + adn + ae[j]));
        den += ex;
      }
      int cnt = min(64, end - base);
      for (int t = 0; t < cnt; ++t) {
        int sj = __shfl(s, t);
        float w = __shfl(ex, t);
        acc = fmaf(w, __half2float(xp[((size_t)sj << 6) + lane]), acc);
      }
    }
    den = wred_sum(den);
  }

  den += exl;
  acc = fmaf(exl, __half2float(xp[((size_t)n << 6) + lane]), acc);
  float h = fmaxf(acc / (den + 1e-16f) + b2[lane], 0.f);
  float p = wred_sum(h * lin_w[lane]);
  if (lane == 0) out[n] = 1.f / (1.f + __expf(-(p + lin_b[0])));
}

// ---------------- host glue ----------------
extern "C" void kernel_launch(void* const* d_in, const int* in_sizes, int n_in,
                              void* d_out, int out_size, void* d_ws, size_t ws_size,
                              hipStream_t stream) {
  const float* x    = (const float*)d_in[0];
  const int*   ei   = (const int*)d_in[1];
  const float* ea   = (const float*)d_in[2];
  const float* W0   = (const float*)d_in[3];
  const float* as0w = (const float*)d_in[4];
  const float* ad0w = (const float*)d_in[5];
  const float* We0  = (const float*)d_in[6];
  const float* ae0w = (const float*)d_in[7];
  const float* b0   = (const float*)d_in[8];
  const float* W1   = (const float*)d_in[9];
  const float* as1w = (const float*)d_in[10];
  const float* ad1w = (const float*)d_in[11];
  const float* We1  = (const float*)d_in[12];
  const float* ae1w = (const float*)d_in[13];
  const float* b1   = (const float*)d_in[14];
  const float* W2   = (const float*)d_in[15];
  const float* as2w = (const float*)d_in[16];
  const float* ad2w = (const float*)d_in[17];
  const float* We2  = (const float*)d_in[18];
  const float* ae2w = (const float*)d_in[19];
  const float* b2   = (const float*)d_in[20];
  const float* linw = (const float*)d_in[21];
  const float* linb = (const float*)d_in[22];

  const int N = in_sizes[0] / 128;
  const int E = in_sizes[1] / 2;
  const int* src = ei;
  const int* dst = ei + E;

  char* p = (char*)d_ws;
  auto alloc = [&](size_t bytes) {
    char* r = p;
    p += (bytes + 255) & ~size_t(255);
    return r;
  };
  __half*        bufAh = (__half*)alloc((size_t)N * 256 * 2);
  unsigned char* xp8   = (unsigned char*)alloc((size_t)N * 256);  // fp8 gather table L0/L1
  __half*        xph2  = (__half*)alloc((size_t)N * 64 * 2);      // fp16 table L2
  __half*        W0t   = (__half*)alloc((size_t)256 * 128 * 2);
  __half*        W1t   = (__half*)alloc((size_t)256 * 256 * 2);
  __half*        W2t   = (__half*)alloc((size_t)64 * 256 * 2);
  // contiguous zero region: deg + all asad buffers (atomicAdd targets)
  char*   zbase      = p;
  int*    deg        = (int*)alloc((size_t)N * 4);
  float*  asb0       = (float*)alloc((size_t)N * 4 * 4);
  float*  adb0       = (float*)alloc((size_t)N * 4 * 4);
  float*  asb1       = (float*)alloc((size_t)N * 4 * 4);
  float*  adb1       = (float*)alloc((size_t)N * 4 * 4);
  float*  asb2       = (float*)alloc((size_t)N * 4);
  float*  adb2       = (float*)alloc((size_t)N * 4);
  size_t  zspan      = (size_t)(p - zbase);
  int*    rank       = (int*)alloc((size_t)E * 4);
  int2*   se         = (int2*)alloc((size_t)E * 8);
  float*  ae0s       = (float*)alloc((size_t)E * 4 * 4);
  float*  ae1s       = (float*)alloc((size_t)E * 4 * 4);
  float*  ae2s       = (float*)alloc((size_t)E * 4);
  int*    row_start  = (int*)alloc((size_t)(N + 1) * 4);
  int*    bsum       = (int*)alloc((size_t)256 * 4);
  float*  wv         = (float*)alloc(144 * 4);

  int nb = (N + 255) / 256;
  int eb = (E + 255) / 256;
  hipMemsetAsync(zbase, 0, zspan, stream);
  count_rank<<<eb, 256, 0, stream>>>(dst, deg, rank, E);
  scan_part<<<nb, 256, 0, stream>>>(deg, bsum, N);
  scan_final<<<nb, 256, 0, stream>>>(deg, bsum, row_start, N, nb);
  scatter_edges<<<eb, 256, 0, stream>>>(src, dst, row_start, rank, se, E);
  prep_weights<<<449, 256, 0, stream>>>(W0, W0t, W1, W1t, W2, W2t,
                                        We0, ae0w, We1, ae1w, We2, ae2w, wv);
  edge_ae<<<eb, 256, 0, stream>>>(ea, se, wv, ae0s, ae1s, ae2s, E);

  int gm = (N + 127) / 128;
  int gm64 = (N + 63) / 64;
  int nwb = (N + 3) / 4;
  // layer 0: A = x (f32, converted during staging); C -> fp8 table; fused asad (atomic)
  gemm_f16mfma<128, 64, true, 4, true><<<dim3(gm, 4), 256, 0, stream>>>(
      x, W0t, xp8, as0w, ad0w, asb0, adb0, N, 128, 256);
  agg_heads4<<<nwb, 256, 0, stream>>>(xp8, se, row_start, asb0, adb0, ae0s, b0, bufAh, N);
  // layer 1
  gemm_f16mfma<128, 64, false, 4, true><<<dim3(gm, 4), 256, 0, stream>>>(
      bufAh, W1t, xp8, as1w, ad1w, asb1, adb1, N, 256, 256);
  agg_heads4<<<nwb, 256, 0, stream>>>(xp8, se, row_start, asb1, adb1, ae1s, b1, bufAh, N);
  // layer 2 (fp16 table) + final linear + sigmoid
  gemm_f16mfma<64, 64, false, 1, false><<<dim3(gm64, 1), 256, 0, stream>>>(
      bufAh, W2t, xph2, as2w, ad2w, asb2, adb2, N, 256, 64);
  agg1_final<<<nwb, 256, 0, stream>>>(xph2, se, row_start, asb2, adb2, ae2s, b2, linw, linb,
                                      (float*)d_out, N);
}

// Round 17
// 287.876 us; speedup vs baseline: 1.1773x; 1.1773x over previous
//
#include <hip/hip_runtime.h>
#include <hip/hip_fp16.h>

using f16x8 = __attribute__((ext_vector_type(8))) _Float16;
using f32x4 = __attribute__((ext_vector_type(4))) float;
using f32x2v = __attribute__((ext_vector_type(2))) float;

// ---------------- wave helpers (wave = 64 lanes on CDNA) ----------------
static __device__ __forceinline__ float wred_sum(float v) {
#pragma unroll
  for (int o = 32; o > 0; o >>= 1) v += __shfl_xor(v, o);
  return v;
}
static __device__ __forceinline__ float lrelu(float x) { return x > 0.f ? x : 0.2f * x; }

// ---------------- preprocessing ----------------
__global__ void count_rank(const int* __restrict__ dst, int* __restrict__ deg,
                           int* __restrict__ rank, int E) {
  int i = blockIdx.x * blockDim.x + threadIdx.x;
  if (i < E) rank[i] = atomicAdd(&deg[dst[i]], 1);
}

__global__ __launch_bounds__(256) void scan_part(const int* __restrict__ deg,
                                                 int* __restrict__ bsum, int n) {
  __shared__ int sd[256];
  int tid = threadIdx.x;
  int i = blockIdx.x * 256 + tid;
  sd[tid] = (i < n) ? deg[i] : 0;
  __syncthreads();
#pragma unroll
  for (int d = 128; d > 0; d >>= 1) {
    if (tid < d) sd[tid] += sd[tid + d];
    __syncthreads();
  }
  if (tid == 0) bsum[blockIdx.x] = sd[0];
}

__global__ __launch_bounds__(256) void scan_final(const int* __restrict__ deg,
                                                  const int* __restrict__ bsum,
                                                  int* __restrict__ row_start, int n, int nb) {
  __shared__ int sd[256];
  __shared__ int sbase;
  int tid = threadIdx.x;
  int b = blockIdx.x;
  int v = (tid < nb && tid < b) ? bsum[tid] : 0;
  sd[tid] = v;
  __syncthreads();
#pragma unroll
  for (int d = 128; d > 0; d >>= 1) {
    if (tid < d) sd[tid] += sd[tid + d];
    __syncthreads();
  }
  if (tid == 0) sbase = sd[0];
  __syncthreads();
  int i = b * 256 + tid;
  int dv = (i < n) ? deg[i] : 0;
  sd[tid] = dv;
  __syncthreads();
#pragma unroll
  for (int d = 1; d < 256; d <<= 1) {
    int t = (tid >= d) ? sd[tid - d] : 0;
    __syncthreads();
    sd[tid] += t;
    __syncthreads();
  }
  int incl = sd[tid];
  if (i < n) row_start[i] = sbase + incl - dv;
  if (i == n - 1) row_start[n] = sbase + incl;
}

__global__ void scatter_edges(const int* __restrict__ src, const int* __restrict__ dst,
                              const int* __restrict__ row_start, const int* __restrict__ rank,
                              int2* __restrict__ se, int E) {
  int i = blockIdx.x * blockDim.x + threadIdx.x;
  if (i < E) {
    int d = dst[i];
    int pos = row_start[d] + rank[i];
    se[pos] = make_int2(src[i], i);
  }
}

// ---------------- fused weight prep: 3 transposes + wvec in one launch ----------------
__global__ __launch_bounds__(256) void prep_weights(
    const float* __restrict__ W0, __half* __restrict__ W0t,
    const float* __restrict__ W1, __half* __restrict__ W1t,
    const float* __restrict__ W2, __half* __restrict__ W2t,
    const float* __restrict__ We0, const float* __restrict__ ae0w,
    const float* __restrict__ We1, const float* __restrict__ ae1w,
    const float* __restrict__ We2, const float* __restrict__ ae2w,
    float* __restrict__ wv) {
  int b = blockIdx.x;
  if (b >= 448) {  // wvec block
    int t = threadIdx.x;
    if (t < 144) {
      int k = t >> 4, d = t & 15;
      const float* We; const float* aev; int h; int HC;
      if (k < 4)      { We = We0; aev = ae0w; h = k;     HC = 256; }
      else if (k < 8) { We = We1; aev = ae1w; h = k - 4; HC = 256; }
      else            { We = We2; aev = ae2w; h = 0;     HC = 64; }
      float sum = 0.f;
#pragma unroll
      for (int c = 0; c < 64; ++c) sum += We[(size_t)d * HC + h * 64 + c] * aev[h * 64 + c];
      wv[k * 16 + d] = sum;
    }
    return;
  }
  const float* W; __half* Wt; int K, Nc, bx, by;
  if (b < 128)      { W = W0; Wt = W0t; K = 128; Nc = 256; bx = b & 15; by = b >> 4; }
  else if (b < 384) { int c = b - 128; W = W1; Wt = W1t; K = 256; Nc = 256; bx = c & 15; by = c >> 4; }
  else              { int c = b - 384; W = W2; Wt = W2t; K = 256; Nc = 64;  bx = c & 3;  by = c >> 2; }
  int n = bx * 16 + (threadIdx.x & 15);
  int k = by * 16 + (threadIdx.x >> 4);
  if (n < Nc && k < K) Wt[(size_t)n * K + k] = __float2half(W[(size_t)k * Nc + n]);
}

// per-edge attention coefficients, CSR-sorted order (random READ, coalesced writes)
__global__ __launch_bounds__(256) void edge_ae(const float* __restrict__ ea,
                                               const int2* __restrict__ se,
                                               const float* __restrict__ wv,
                                               float* __restrict__ ae0, float* __restrict__ ae1,
                                               float* __restrict__ ae2, int E) {
  __shared__ float swv[144];
  if (threadIdx.x < 144) swv[threadIdx.x] = wv[threadIdx.x];
  __syncthreads();
  int p = blockIdx.x * blockDim.x + threadIdx.x;
  if (p >= E) return;
  int e = se[p].y;
  const float4* er = (const float4*)(ea + (size_t)e * 16);
  float4 v0 = er[0], v1 = er[1], v2 = er[2], v3 = er[3];
  float ev[16] = {v0.x, v0.y, v0.z, v0.w, v1.x, v1.y, v1.z, v1.w,
                  v2.x, v2.y, v2.z, v2.w, v3.x, v3.y, v3.z, v3.w};
  float r[9];
#pragma unroll
  for (int k = 0; k < 9; ++k) {
    float s = 0.f;
#pragma unroll
    for (int d = 0; d < 16; ++d) s += ev[d] * swv[k * 16 + d];
    r[k] = s;
  }
  *(float4*)(ae0 + (size_t)p * 4) = make_float4(r[0], r[1], r[2], r[3]);
  *(float4*)(ae1 + (size_t)p * 4) = make_float4(r[4], r[5], r[6], r[7]);
  ae2[p] = r[8];
}

// ---------------- f16 MFMA GEMM, double-buffered reg-staged pipeline (BK=32) ----------------
// M-split wide grid (BM=64): A read once per column-block, B is L2-resident.
// BN=128 -> WN=64 = one full head per wave-column -> plain asad stores (HS=4).
// BN=64 (layer 2) -> partial dots -> atomicAdd (HS=1, zeroed buffers).
template <int BM, int BN, bool AF32, int HS, bool XF8>
__global__ __launch_bounds__(256) void gemm_f16mfma(const void* __restrict__ Av,
                                                    const __half* __restrict__ Bt,
                                                    void* __restrict__ Cv,
                                                    const float* __restrict__ as_w,
                                                    const float* __restrict__ ad_w,
                                                    float* __restrict__ asb,
                                                    float* __restrict__ adb,
                                                    int M, int K, int Nc) {
  constexpr int BK = 32;
  constexpr int LDT = BK + 8;  // 40 f16 = 80B row stride
  constexpr int WM = BM / 2;
  constexpr int WN = BN / 2;
  constexpr int NFM = WM / 16;
  constexpr int NFN = WN / 16;
  constexpr int NCA = AF32 ? (BM / 32) : (BM / 64);  // A 16B chunks / thread
  constexpr int NCB = BN / 64;
  __shared__ __half As[2][BM][LDT];
  __shared__ __half Bs[2][BN][LDT];
  const int tid = threadIdx.x;
  const int lane = tid & 63, wave = tid >> 6;
  const int wr = wave >> 1, wc = wave & 1;
  const int bm = blockIdx.x * BM;
  const int bn = blockIdx.y * BN;
  const int r15 = lane & 15, kgrp = lane >> 4;
  f32x4 acc[NFM][NFN] = {};
  float4 sa[NCA];
  float4 sb[NCB];

  auto issue_loads = [&](int t) {
    int k0 = t * BK;
    if constexpr (AF32) {
      const float* A = (const float*)Av;
#pragma unroll
      for (int i = 0; i < NCA; ++i) {
        int chunk = tid + i * 256;
        int row = chunk >> 3, kc = (chunk & 7) * 4;
        int grow = bm + row;
        float4 v = make_float4(0, 0, 0, 0);
        if (grow < M) v = *(const float4*)(A + (size_t)grow * K + k0 + kc);
        sa[i] = v;
      }
    } else {
      const __half* A = (const __half*)Av;
#pragma unroll
      for (int i = 0; i < NCA; ++i) {
        int chunk = tid + i * 256;
        int row = chunk >> 2, kc = (chunk & 3) * 8;
        int grow = bm + row;
        float4 v = make_float4(0, 0, 0, 0);
        if (grow < M) v = *(const float4*)(A + (size_t)grow * K + k0 + kc);
        sa[i] = v;
      }
    }
#pragma unroll
    for (int i = 0; i < NCB; ++i) {
      int chunk = tid + i * 256;
      int row = chunk >> 2, kc = (chunk & 3) * 8;
      sb[i] = *(const float4*)(Bt + (size_t)(bn + row) * K + t * BK + kc);
    }
  };
  auto write_lds = [&](int buf) {
    if constexpr (AF32) {
#pragma unroll
      for (int i = 0; i < NCA; ++i) {
        int chunk = tid + i * 256;
        int row = chunk >> 3, kc = (chunk & 7) * 4;
        float4 v = sa[i];
        __half2 h01 = __floats2half2_rn(v.x, v.y);
        __half2 h23 = __floats2half2_rn(v.z, v.w);
        uint2 u;
        u.x = *(unsigned*)&h01;
        u.y = *(unsigned*)&h23;
        *(uint2*)&As[buf][row][kc] = u;
      }
    } else {
#pragma unroll
      for (int i = 0; i < NCA; ++i) {
        int chunk = tid + i * 256;
        int row = chunk >> 2, kc = (chunk & 3) * 8;
        *(float4*)&As[buf][row][kc] = sa[i];
      }
    }
#pragma unroll
    for (int i = 0; i < NCB; ++i) {
      int chunk = tid + i * 256;
      int row = chunk >> 2, kc = (chunk & 3) * 8;
      *(float4*)&Bs[buf][row][kc] = sb[i];
    }
  };
  auto compute = [&](int buf) {
    f16x8 af[NFM], bf[NFN];
#pragma unroll
    for (int mi = 0; mi < NFM; ++mi)
      af[mi] = *(const f16x8*)&As[buf][wr * WM + mi * 16 + r15][kgrp * 8];
#pragma unroll
    for (int ni = 0; ni < NFN; ++ni)
      bf[ni] = *(const f16x8*)&Bs[buf][wc * WN + ni * 16 + r15][kgrp * 8];
#pragma unroll
    for (int mi = 0; mi < NFM; ++mi)
#pragma unroll
      for (int ni = 0; ni < NFN; ++ni)
        acc[mi][ni] = __builtin_amdgcn_mfma_f32_16x16x32_f16(af[mi], bf[ni], acc[mi][ni], 0, 0, 0);
  };

  const int nt = K / BK;
  issue_loads(0);
  write_lds(0);
  __syncthreads();
  for (int t = 0; t < nt; ++t) {
    int cur = t & 1;
    if (t + 1 < nt) issue_loads(t + 1);
    compute(cur);
    if (t + 1 < nt) {
      write_lds(cur ^ 1);
      __syncthreads();
    }
  }

  float asw[NFN], adw[NFN];
#pragma unroll
  for (int ni = 0; ni < NFN; ++ni) {
    int gcol = bn + wc * WN + ni * 16 + r15;
    asw[ni] = as_w[gcol];
    adw[ni] = ad_w[gcol];
  }
  const int hidx = (bn + wc * WN) >> 6;
#pragma unroll
  for (int mi = 0; mi < NFM; ++mi) {
#pragma unroll
    for (int r = 0; r < 4; ++r) {
      int grow = bm + wr * WM + mi * 16 + kgrp * 4 + r;
      bool valid = grow < M;
      float sdot = 0.f, ddot = 0.f;
#pragma unroll
      for (int ni = 0; ni < NFN; ++ni) {
        float v = acc[mi][ni][r];
        if (valid) {
          int gcol = bn + wc * WN + ni * 16 + r15;
          if constexpr (XF8) {
            unsigned pk = (unsigned)__builtin_amdgcn_cvt_pk_fp8_f32(v, v, 0, false);
            ((unsigned char*)Cv)[(size_t)grow * Nc + gcol] = (unsigned char)(pk & 0xff);
          } else {
            ((__half*)Cv)[(size_t)grow * Nc + gcol] = __float2half(v);
          }
        }
        sdot = fmaf(v, asw[ni], sdot);
        ddot = fmaf(v, adw[ni], ddot);
      }
#pragma unroll
      for (int o = 8; o >= 1; o >>= 1) {
        sdot += __shfl_xor(sdot, o);
        ddot += __shfl_xor(ddot, o);
      }
      if (valid && r15 == 0) {
        if constexpr (HS == 1) {
          atomicAdd(&asb[grow], sdot);
          atomicAdd(&adb[grow], ddot);
        } else {
          asb[(size_t)grow * HS + hidx] = sdot;
          adb[(size_t)grow * HS + hidx] = ddot;
        }
      }
    }
  }
}

// ---------------- fused segment-softmax + aggregation, heads=4 C=64, fp8 gather ----------------
// softmax WITHOUT max subtraction (shift-invariant; logits far below f32 exp overflow)
__global__ __launch_bounds__(256) void agg_heads4(
    const unsigned char* __restrict__ xp, const int2* __restrict__ se,
    const int* __restrict__ row_start, const float* __restrict__ asb,
    const float* __restrict__ adb, const float* __restrict__ ae,
    const float* __restrict__ bias, __half* __restrict__ out, int N) {
  __shared__ float sw[4][256];
  __shared__ int ssrc[4][64];  // pre-shifted row byte offsets (s << 8)
  int wave = threadIdx.x >> 6, lane = threadIdx.x & 63;
  int n = blockIdx.x * 4 + wave;
  if (n >= N) return;
  int beg = row_start[n], end = row_start[n + 1];
  int deg = end - beg;
  int hsel = lane >> 4;
  float4 adn = *(const float4*)(adb + (size_t)n * 4);
  float4 asn = *(const float4*)(asb + (size_t)n * 4);
  float invd = 1.f / fmaxf((float)deg, 1.f);
  float acc0 = 0, acc1 = 0, acc2 = 0, acc3 = 0;
  float den0 = 0, den1 = 0, den2 = 0, den3 = 0;
  float al0, al1, al2, al3, exl0, exl1, exl2, exl3;
  const int loff = lane << 2;  // 4 fp8 bytes / lane

  if (deg <= 64) {
    int j = beg + lane;
    bool act = j < end;
    int s = 0;
    float4 asv = make_float4(0, 0, 0, 0), aev = make_float4(0, 0, 0, 0);
    if (act) {
      s = se[j].x;
      asv = *(const float4*)(asb + (size_t)s * 4);
      aev = *(const float4*)(ae + (size_t)j * 4);
    }
    float ex0 = act ? __expf(lrelu(asv.x + adn.x + aev.x)) : 0.f;
    float ex1 = act ? __expf(lrelu(asv.y + adn.y + aev.y)) : 0.f;
    float ex2 = act ? __expf(lrelu(asv.z + adn.z + aev.z)) : 0.f;
    float ex3 = act ? __expf(lrelu(asv.w + adn.w + aev.w)) : 0.f;
    float aes0 = wred_sum(aev.x), aes1 = wred_sum(aev.y), aes2 = wred_sum(aev.z), aes3 = wred_sum(aev.w);
    al0 = lrelu(asn.x + adn.x + aes0 * invd);
    al1 = lrelu(asn.y + adn.y + aes1 * invd);
    al2 = lrelu(asn.z + adn.z + aes2 * invd);
    al3 = lrelu(asn.w + adn.w + aes3 * invd);
    exl0 = __expf(al0); exl1 = __expf(al1); exl2 = __expf(al2); exl3 = __expf(al3);
    den0 = wred_sum(ex0); den1 = wred_sum(ex1); den2 = wred_sum(ex2); den3 = wred_sum(ex3);
    *(float4*)&sw[wave][lane << 2] = make_float4(ex0, ex1, ex2, ex3);
    ssrc[wave][lane] = s << 8;
    asm volatile("" ::: "memory");
    int cnt = deg;
    int sj0 = ssrc[wave][0], sj1 = ssrc[wave][1], sj2 = ssrc[wave][2], sj3 = ssrc[wave][3];
    unsigned B0 = *(const unsigned*)(xp + sj0 + loff);
    unsigned B1 = *(const unsigned*)(xp + sj1 + loff);
    unsigned B2 = *(const unsigned*)(xp + sj2 + loff);
    unsigned B3 = *(const unsigned*)(xp + sj3 + loff);
    for (int t = 0; t < cnt; t += 4) {
      {
        float w = sw[wave][((t + 0) << 2) + hsel];
        f32x2v lo = __builtin_amdgcn_cvt_pk_f32_fp8((int)B0, false);
        f32x2v hi = __builtin_amdgcn_cvt_pk_f32_fp8((int)B0, true);
        acc0 = fmaf(w, lo[0], acc0); acc1 = fmaf(w, lo[1], acc1);
        acc2 = fmaf(w, hi[0], acc2); acc3 = fmaf(w, hi[1], acc3);
        int ns = ssrc[wave][(t + 4) & 63];
        B0 = *(const unsigned*)(xp + ns + loff);
      }
      {
        float w = sw[wave][((t + 1) << 2) + hsel];
        f32x2v lo = __builtin_amdgcn_cvt_pk_f32_fp8((int)B1, false);
        f32x2v hi = __builtin_amdgcn_cvt_pk_f32_fp8((int)B1, true);
        acc0 = fmaf(w, lo[0], acc0); acc1 = fmaf(w, lo[1], acc1);
        acc2 = fmaf(w, hi[0], acc2); acc3 = fmaf(w, hi[1], acc3);
        int ns = ssrc[wave][(t + 5) & 63];
        B1 = *(const unsigned*)(xp + ns + loff);
      }
      {
        float w = sw[wave][((t + 2) << 2) + hsel];
        f32x2v lo = __builtin_amdgcn_cvt_pk_f32_fp8((int)B2, false);
        f32x2v hi = __builtin_amdgcn_cvt_pk_f32_fp8((int)B2, true);
        acc0 = fmaf(w, lo[0], acc0); acc1 = fmaf(w, lo[1], acc1);
        acc2 = fmaf(w, hi[0], acc2); acc3 = fmaf(w, hi[1], acc3);
        int ns = ssrc[wave][(t + 6) & 63];
        B2 = *(const unsigned*)(xp + ns + loff);
      }
      {
        float w = sw[wave][((t + 3) << 2) + hsel];
        f32x2v lo = __builtin_amdgcn_cvt_pk_f32_fp8((int)B3, false);
        f32x2v hi = __builtin_amdgcn_cvt_pk_f32_fp8((int)B3, true);
        acc0 = fmaf(w, lo[0], acc0); acc1 = fmaf(w, lo[1], acc1);
        acc2 = fmaf(w, hi[0], acc2); acc3 = fmaf(w, hi[1], acc3);
        int ns = ssrc[wave][(t + 7) & 63];
        B3 = *(const unsigned*)(xp + ns + loff);
      }
    }
  } else {
    float aes0 = 0, aes1 = 0, aes2 = 0, aes3 = 0;
    for (int base = beg; base < end; base += 64) {
      int j = base + lane;
      if (j < end) {
        float4 aev = *(const float4*)(ae + (size_t)j * 4);
        aes0 += aev.x; aes1 += aev.y; aes2 += aev.z; aes3 += aev.w;
      }
    }
    aes0 = wred_sum(aes0); aes1 = wred_sum(aes1); aes2 = wred_sum(aes2); aes3 = wred_sum(aes3);
    al0 = lrelu(asn.x + adn.x + aes0 * invd);
    al1 = lrelu(asn.y + adn.y + aes1 * invd);
    al2 = lrelu(asn.z + adn.z + aes2 * invd);
    al3 = lrelu(asn.w + adn.w + aes3 * invd);
    exl0 = __expf(al0); exl1 = __expf(al1); exl2 = __expf(al2); exl3 = __expf(al3);
    for (int base = beg; base < end; base += 64) {
      int j = base + lane;
      float ex0 = 0, ex1 = 0, ex2 = 0, ex3 = 0;
      int s = 0;
      if (j < end) {
        s = se[j].x;
        float4 asv = *(const float4*)(asb + (size_t)s * 4);
        float4 aev = *(const float4*)(ae + (size_t)j * 4);
        ex0 = __expf(lrelu(asv.x + adn.x + aev.x));
        ex1 = __expf(lrelu(asv.y + adn.y + aev.y));
        ex2 = __expf(lrelu(asv.z + adn.z + aev.z));
        ex3 = __expf(lrelu(asv.w + adn.w + aev.w));
        den0 += ex0; den1 += ex1; den2 += ex2; den3 += ex3;
      }
      int cnt = min(64, end - base);
      for (int t = 0; t < cnt; ++t) {
        int sj = __shfl(s, t);
        float w0 = __shfl(ex0, t), w1 = __shfl(ex1, t), w2 = __shfl(ex2, t), w3 = __shfl(ex3, t);
        float w = hsel == 0 ? w0 : (hsel == 1 ? w1 : (hsel == 2 ? w2 : w3));
        unsigned u = *(const unsigned*)(xp + ((size_t)sj << 8) + loff);
        f32x2v lo = __builtin_amdgcn_cvt_pk_f32_fp8((int)u, false);
        f32x2v hi = __builtin_amdgcn_cvt_pk_f32_fp8((int)u, true);
        acc0 = fmaf(w, lo[0], acc0);
        acc1 = fmaf(w, lo[1], acc1);
        acc2 = fmaf(w, hi[0], acc2);
        acc3 = fmaf(w, hi[1], acc3);
      }
    }
    den0 = wred_sum(den0); den1 = wred_sum(den1); den2 = wred_sum(den2); den3 = wred_sum(den3);
  }

  den0 += exl0; den1 += exl1; den2 += exl2; den3 += exl3;
  float exh = hsel == 0 ? exl0 : (hsel == 1 ? exl1 : (hsel == 2 ? exl2 : exl3));
  {
    unsigned u = *(const unsigned*)(xp + ((size_t)n << 8) + loff);
    f32x2v lo = __builtin_amdgcn_cvt_pk_f32_fp8((int)u, false);
    f32x2v hi = __builtin_amdgcn_cvt_pk_f32_fp8((int)u, true);
    acc0 = fmaf(exh, lo[0], acc0);
    acc1 = fmaf(exh, lo[1], acc1);
    acc2 = fmaf(exh, hi[0], acc2);
    acc3 = fmaf(exh, hi[1], acc3);
  }
  float denh = hsel == 0 ? den0 : (hsel == 1 ? den1 : (hsel == 2 ? den2 : den3));
  float rden = 1.f / (denh + 1e-16f);
  float4 bv = *(const float4*)(bias + (lane << 2));
  __half2 o01 = __floats2half2_rn(fmaxf(acc0 * rden + bv.x, 0.f), fmaxf(acc1 * rden + bv.y, 0.f));
  __half2 o23 = __floats2half2_rn(fmaxf(acc2 * rden + bv.z, 0.f), fmaxf(acc3 * rden + bv.w, 0.f));
  uint2 u;
  u.x = *(unsigned*)&o01;
  u.y = *(unsigned*)&o23;
  *(uint2*)(out + (size_t)n * 256 + (lane << 2)) = u;
}

// ---------------- layer2 (heads=1, fp16 table) + final linear + sigmoid, fused ----------------
__global__ __launch_bounds__(256) void agg1_final(
    const __half* __restrict__ xp, const int2* __restrict__ se,
    const int* __restrict__ row_start, const float* __restrict__ asb,
    const float* __restrict__ adb, const float* __restrict__ ae,
    const float* __restrict__ b2, const float* __restrict__ lin_w,
    const float* __restrict__ lin_b, float* __restrict__ out, int N) {
  __shared__ float sw1[4][64];
  __shared__ int ssrc1[4][64];
  int wave = threadIdx.x >> 6, lane = threadIdx.x & 63;
  int n = blockIdx.x * 4 + wave;
  if (n >= N) return;
  int beg = row_start[n], end = row_start[n + 1];
  int deg = end - beg;
  float adn = adb[n], asn = asb[n];
  float invd = 1.f / fmaxf((float)deg, 1.f);
  float al, exl, acc = 0, den = 0;

  if (deg <= 64) {
    int j = beg + lane;
    bool act = j < end;
    int s = 0;
    float aev = 0, asvs = 0;
    if (act) { s = se[j].x; aev = ae[j]; asvs = asb[s]; }
    float ex = act ? __expf(lrelu(asvs + adn + aev)) : 0.f;
    float aes = wred_sum(aev);
    al = lrelu(asn + adn + aes * invd);
    exl = __expf(al);
    den = wred_sum(ex);
    sw1[wave][lane] = ex;
    ssrc1[wave][lane] = s;
    asm volatile("" ::: "memory");
    int cnt = deg;
    int sj0 = ssrc1[wave][0], sj1 = ssrc1[wave][1], sj2 = ssrc1[wave][2], sj3 = ssrc1[wave][3];
    __half H0 = xp[((size_t)sj0 << 6) + lane];
    __half H1 = xp[((size_t)sj1 << 6) + lane];
    __half H2 = xp[((size_t)sj2 << 6) + lane];
    __half H3 = xp[((size_t)sj3 << 6) + lane];
    for (int t = 0; t < cnt; t += 4) {
      {
        float w = sw1[wave][t + 0];
        acc = fmaf(w, __half2float(H0), acc);
        int ns = ssrc1[wave][(t + 4) & 63];
        H0 = xp[((size_t)ns << 6) + lane];
      }
      {
        float w = sw1[wave][t + 1];
        acc = fmaf(w, __half2float(H1), acc);
        int ns = ssrc1[wave][(t + 5) & 63];
        H1 = xp[((size_t)ns << 6) + lane];
      }
      {
        float w = sw1[wave][t + 2];
        acc = fmaf(w, __half2float(H2), acc);
        int ns = ssrc1[wave][(t + 6) & 63];
        H2 = xp[((size_t)ns << 6) + lane];
      }
      {
        float w = sw1[wave][t + 3];
        acc = fmaf(w, __half2float(H3), acc);
        int ns = ssrc1[wave][(t + 7) & 63];
        H3 = xp[((size_t)ns << 6) + lane];
      }
    }
  } else {
    float aes = 0;
    for (int base = beg; base < end; base += 64) {
      int j = base + lane;
      if (j < end) aes += ae[j];
    }
    aes = wred_sum(aes);
    al = lrelu(asn + adn + aes * invd);
    exl = __expf(al);
    for (int base = beg; base < end; base += 64) {
      int j = base + lane;
      float ex = 0;
      int s = 0;
      if (j < end) {
        s = se[j].x;
        ex = __expf(lrelu(asb[s] + adn + ae[j]));
        den += ex;
      }
      int cnt = min(64, end - base);
      for (int t = 0; t < cnt; ++t) {
        int sj = __shfl(s, t);
        float w = __shfl(ex, t);
        acc = fmaf(w, __half2float(xp[((size_t)sj << 6) + lane]), acc);
      }
    }
    den = wred_sum(den);
  }

  den += exl;
  acc = fmaf(exl, __half2float(xp[((size_t)n << 6) + lane]), acc);
  float h = fmaxf(acc / (den + 1e-16f) + b2[lane], 0.f);
  float p = wred_sum(h * lin_w[lane]);
  if (lane == 0) out[n] = 1.f / (1.f + __expf(-(p + lin_b[0])));
}

// ---------------- host glue ----------------
extern "C" void kernel_launch(void* const* d_in, const int* in_sizes, int n_in,
                              void* d_out, int out_size, void* d_ws, size_t ws_size,
                              hipStream_t stream) {
  const float* x    = (const float*)d_in[0];
  const int*   ei   = (const int*)d_in[1];
  const float* ea   = (const float*)d_in[2];
  const float* W0   = (const float*)d_in[3];
  const float* as0w = (const float*)d_in[4];
  const float* ad0w = (const float*)d_in[5];
  const float* We0  = (const float*)d_in[6];
  const float* ae0w = (const float*)d_in[7];
  const float* b0   = (const float*)d_in[8];
  const float* W1   = (const float*)d_in[9];
  const float* as1w = (const float*)d_in[10];
  const float* ad1w = (const float*)d_in[11];
  const float* We1  = (const float*)d_in[12];
  const float* ae1w = (const float*)d_in[13];
  const float* b1   = (const float*)d_in[14];
  const float* W2   = (const float*)d_in[15];
  const float* as2w = (const float*)d_in[16];
  const float* ad2w = (const float*)d_in[17];
  const float* We2  = (const float*)d_in[18];
  const float* ae2w = (const float*)d_in[19];
  const float* b2   = (const float*)d_in[20];
  const float* linw = (const float*)d_in[21];
  const float* linb = (const float*)d_in[22];

  const int N = in_sizes[0] / 128;
  const int E = in_sizes[1] / 2;
  const int* src = ei;
  const int* dst = ei + E;

  char* p = (char*)d_ws;
  auto alloc = [&](size_t bytes) {
    char* r = p;
    p += (bytes + 255) & ~size_t(255);
    return r;
  };
  __half*        bufAh = (__half*)alloc((size_t)N * 256 * 2);
  unsigned char* xp8   = (unsigned char*)alloc((size_t)N * 256);  // fp8 gather table L0/L1
  __half*        xph2  = (__half*)alloc((size_t)N * 64 * 2);      // fp16 table L2
  __half*        W0t   = (__half*)alloc((size_t)256 * 128 * 2);
  __half*        W1t   = (__half*)alloc((size_t)256 * 256 * 2);
  __half*        W2t   = (__half*)alloc((size_t)64 * 256 * 2);
  float*         asb0  = (float*)alloc((size_t)N * 4 * 4);
  float*         adb0  = (float*)alloc((size_t)N * 4 * 4);
  float*         asb1  = (float*)alloc((size_t)N * 4 * 4);
  float*         adb1  = (float*)alloc((size_t)N * 4 * 4);
  // contiguous zero region: deg, asb2, adb2 (atomic targets)
  char*   zbase      = p;
  int*    deg        = (int*)alloc((size_t)N * 4);
  float*  asb2       = (float*)alloc((size_t)N * 4);
  float*  adb2       = (float*)alloc((size_t)N * 4);
  size_t  zspan      = (size_t)(p - zbase);
  int*    rank       = (int*)alloc((size_t)E * 4);
  int2*   se         = (int2*)alloc((size_t)E * 8);
  float*  ae0s       = (float*)alloc((size_t)E * 4 * 4);
  float*  ae1s       = (float*)alloc((size_t)E * 4 * 4);
  float*  ae2s       = (float*)alloc((size_t)E * 4);
  int*    row_start  = (int*)alloc((size_t)(N + 1) * 4);
  int*    bsum       = (int*)alloc((size_t)256 * 4);
  float*  wv         = (float*)alloc(144 * 4);

  int nb = (N + 255) / 256;
  int eb = (E + 255) / 256;
  hipMemsetAsync(zbase, 0, zspan, stream);
  count_rank<<<eb, 256, 0, stream>>>(dst, deg, rank, E);
  scan_part<<<nb, 256, 0, stream>>>(deg, bsum, N);
  scan_final<<<nb, 256, 0, stream>>>(deg, bsum, row_start, N, nb);
  scatter_edges<<<eb, 256, 0, stream>>>(src, dst, row_start, rank, se, E);
  prep_weights<<<449, 256, 0, stream>>>(W0, W0t, W1, W1t, W2, W2t,
                                        We0, ae0w, We1, ae1w, We2, ae2w, wv);
  edge_ae<<<eb, 256, 0, stream>>>(ea, se, wv, ae0s, ae1s, ae2s, E);

  int gm64 = (N + 63) / 64;
  int nwb = (N + 3) / 4;
  // layer 0: A = x (f32, converted during staging); C -> fp8 table; fused asad (plain stores)
  gemm_f16mfma<64, 128, true, 4, true><<<dim3(gm64, 2), 256, 0, stream>>>(
      x, W0t, xp8, as0w, ad0w, asb0, adb0, N, 128, 256);
  agg_heads4<<<nwb, 256, 0, stream>>>(xp8, se, row_start, asb0, adb0, ae0s, b0, bufAh, N);
  // layer 1
  gemm_f16mfma<64, 128, false, 4, true><<<dim3(gm64, 2), 256, 0, stream>>>(
      bufAh, W1t, xp8, as1w, ad1w, asb1, adb1, N, 256, 256);
  agg_heads4<<<nwb, 256, 0, stream>>>(xp8, se, row_start, asb1, adb1, ae1s, b1, bufAh, N);
  // layer 2 (fp16 table) + final linear + sigmoid (atomic asad)
  gemm_f16mfma<64, 64, false, 1, false><<<dim3(gm64, 1), 256, 0, stream>>>(
      bufAh, W2t, xph2, as2w, ad2w, asb2, adb2, N, 256, 64);
  agg1_final<<<nwb, 256, 0, stream>>>(xph2, se, row_start, asb2, adb2, ae2s, b2, linw, linb,
                                      (float*)d_out, N);
}

// Round 18
// 272.570 us; speedup vs baseline: 1.2434x; 1.0562x over previous
//
#include <hip/hip_runtime.h>
#include <hip/hip_fp16.h>

using f16x8 = __attribute__((ext_vector_type(8))) _Float16;
using f32x4 = __attribute__((ext_vector_type(4))) float;
using f32x2v = __attribute__((ext_vector_type(2))) float;

// ---------------- wave helpers (wave = 64 lanes on CDNA) ----------------
static __device__ __forceinline__ float wred_sum(float v) {
#pragma unroll
  for (int o = 32; o > 0; o >>= 1) v += __shfl_xor(v, o);
  return v;
}
static __device__ __forceinline__ float lrelu(float x) { return x > 0.f ? x : 0.2f * x; }

// ---------------- preprocessing ----------------
__global__ void count_rank(const int* __restrict__ dst, int* __restrict__ deg,
                           int* __restrict__ rank, int E) {
  int i = blockIdx.x * blockDim.x + threadIdx.x;
  if (i < E) rank[i] = atomicAdd(&deg[dst[i]], 1);
}

__global__ __launch_bounds__(256) void scan_part(const int* __restrict__ deg,
                                                 int* __restrict__ bsum, int n) {
  __shared__ int sd[256];
  int tid = threadIdx.x;
  int i = blockIdx.x * 256 + tid;
  sd[tid] = (i < n) ? deg[i] : 0;
  __syncthreads();
#pragma unroll
  for (int d = 128; d > 0; d >>= 1) {
    if (tid < d) sd[tid] += sd[tid + d];
    __syncthreads();
  }
  if (tid == 0) bsum[blockIdx.x] = sd[0];
}

__global__ __launch_bounds__(256) void scan_final(const int* __restrict__ deg,
                                                  const int* __restrict__ bsum,
                                                  int* __restrict__ row_start, int n, int nb) {
  __shared__ int sd[256];
  __shared__ int sbase;
  int tid = threadIdx.x;
  int b = blockIdx.x;
  int v = (tid < nb && tid < b) ? bsum[tid] : 0;
  sd[tid] = v;
  __syncthreads();
#pragma unroll
  for (int d = 128; d > 0; d >>= 1) {
    if (tid < d) sd[tid] += sd[tid + d];
    __syncthreads();
  }
  if (tid == 0) sbase = sd[0];
  __syncthreads();
  int i = b * 256 + tid;
  int dv = (i < n) ? deg[i] : 0;
  sd[tid] = dv;
  __syncthreads();
#pragma unroll
  for (int d = 1; d < 256; d <<= 1) {
    int t = (tid >= d) ? sd[tid - d] : 0;
    __syncthreads();
    sd[tid] += t;
    __syncthreads();
  }
  int incl = sd[tid];
  if (i < n) row_start[i] = sbase + incl - dv;
  if (i == n - 1) row_start[n] = sbase + incl;
}

__global__ void scatter_edges(const int* __restrict__ src, const int* __restrict__ dst,
                              const int* __restrict__ row_start, const int* __restrict__ rank,
                              int2* __restrict__ se, int E) {
  int i = blockIdx.x * blockDim.x + threadIdx.x;
  if (i < E) {
    int d = dst[i];
    int pos = row_start[d] + rank[i];
    se[pos] = make_int2(src[i], i);
  }
}

// ---------------- fused weight prep: 3 transposes + wvec in one launch ----------------
__global__ __launch_bounds__(256) void prep_weights(
    const float* __restrict__ W0, __half* __restrict__ W0t,
    const float* __restrict__ W1, __half* __restrict__ W1t,
    const float* __restrict__ W2, __half* __restrict__ W2t,
    const float* __restrict__ We0, const float* __restrict__ ae0w,
    const float* __restrict__ We1, const float* __restrict__ ae1w,
    const float* __restrict__ We2, const float* __restrict__ ae2w,
    float* __restrict__ wv) {
  int b = blockIdx.x;
  if (b >= 448) {  // wvec block
    int t = threadIdx.x;
    if (t < 144) {
      int k = t >> 4, d = t & 15;
      const float* We; const float* aev; int h; int HC;
      if (k < 4)      { We = We0; aev = ae0w; h = k;     HC = 256; }
      else if (k < 8) { We = We1; aev = ae1w; h = k - 4; HC = 256; }
      else            { We = We2; aev = ae2w; h = 0;     HC = 64; }
      float sum = 0.f;
#pragma unroll
      for (int c = 0; c < 64; ++c) sum += We[(size_t)d * HC + h * 64 + c] * aev[h * 64 + c];
      wv[k * 16 + d] = sum;
    }
    return;
  }
  const float* W; __half* Wt; int K, Nc, bx, by;
  if (b < 128)      { W = W0; Wt = W0t; K = 128; Nc = 256; bx = b & 15; by = b >> 4; }
  else if (b < 384) { int c = b - 128; W = W1; Wt = W1t; K = 256; Nc = 256; bx = c & 15; by = c >> 4; }
  else              { int c = b - 384; W = W2; Wt = W2t; K = 256; Nc = 64;  bx = c & 3;  by = c >> 2; }
  int n = bx * 16 + (threadIdx.x & 15);
  int k = by * 16 + (threadIdx.x >> 4);
  if (n < Nc && k < K) Wt[(size_t)n * K + k] = __float2half(W[(size_t)k * Nc + n]);
}

// per-edge attention coefficients, CSR-sorted order (random READ, coalesced writes)
__global__ __launch_bounds__(256) void edge_ae(const float* __restrict__ ea,
                                               const int2* __restrict__ se,
                                               const float* __restrict__ wv,
                                               float* __restrict__ ae0, float* __restrict__ ae1,
                                               float* __restrict__ ae2, int E) {
  __shared__ float swv[144];
  if (threadIdx.x < 144) swv[threadIdx.x] = wv[threadIdx.x];
  __syncthreads();
  int p = blockIdx.x * blockDim.x + threadIdx.x;
  if (p >= E) return;
  int e = se[p].y;
  const float4* er = (const float4*)(ea + (size_t)e * 16);
  float4 v0 = er[0], v1 = er[1], v2 = er[2], v3 = er[3];
  float ev[16] = {v0.x, v0.y, v0.z, v0.w, v1.x, v1.y, v1.z, v1.w,
                  v2.x, v2.y, v2.z, v2.w, v3.x, v3.y, v3.z, v3.w};
  float r[9];
#pragma unroll
  for (int k = 0; k < 9; ++k) {
    float s = 0.f;
#pragma unroll
    for (int d = 0; d < 16; ++d) s += ev[d] * swv[k * 16 + d];
    r[k] = s;
  }
  *(float4*)(ae0 + (size_t)p * 4) = make_float4(r[0], r[1], r[2], r[3]);
  *(float4*)(ae1 + (size_t)p * 4) = make_float4(r[4], r[5], r[6], r[7]);
  ae2[p] = r[8];
}

// ---------------- f16 MFMA GEMM, double-buffered reg-staged pipeline (BK=32) ----------------
// XF8: C stored as fp8-e4m3. HS=4: plain asad stores; HS=1: atomicAdd.
template <int BN, bool AF32, int HS, bool XF8>
__global__ __launch_bounds__(256) void gemm_f16mfma(const void* __restrict__ Av,
                                                    const __half* __restrict__ Bt,
                                                    void* __restrict__ Cv,
                                                    const float* __restrict__ as_w,
                                                    const float* __restrict__ ad_w,
                                                    float* __restrict__ asb,
                                                    float* __restrict__ adb,
                                                    int M, int K, int Nc) {
  constexpr int BM = 128, BK = 32;
  constexpr int LDT = BK + 8;  // 40 f16 = 80B row stride
  constexpr int WN = BN / 2;
  constexpr int NFN = WN / 16;
  __shared__ __half As[2][BM][LDT];
  __shared__ __half Bs[2][BN][LDT];
  const int tid = threadIdx.x;
  const int lane = tid & 63, wave = tid >> 6;
  const int wr = wave >> 1, wc = wave & 1;
  const int bm = blockIdx.x * BM;
  const int bn = blockIdx.y * BN;
  const int r15 = lane & 15, kgrp = lane >> 4;
  f32x4 acc[4][NFN] = {};
  // staging registers
  float4 ar32_0, ar32_1, ar32_2, ar32_3;  // AF32: 4 chunks of 4 f32
  float4 ar16_0, ar16_1;                  // f16: 2 chunks of 8 f16
  float4 br_0, br_1;                      // BN/64 chunks

  auto issue_loads = [&](int t) {
    int k0 = t * BK;
    if constexpr (AF32) {
      const float* A = (const float*)Av;
#pragma unroll
      for (int i = 0; i < 4; ++i) {
        int chunk = tid + i * 256;
        int row = chunk >> 3, kc = (chunk & 7) * 4;
        int grow = bm + row;
        float4 v = make_float4(0, 0, 0, 0);
        if (grow < M) v = *(const float4*)(A + (size_t)grow * K + k0 + kc);
        if (i == 0) ar32_0 = v; else if (i == 1) ar32_1 = v;
        else if (i == 2) ar32_2 = v; else ar32_3 = v;
      }
    } else {
      const __half* A = (const __half*)Av;
#pragma unroll
      for (int i = 0; i < 2; ++i) {
        int chunk = tid + i * 256;
        int row = chunk >> 2, kc = (chunk & 3) * 8;
        int grow = bm + row;
        float4 v = make_float4(0, 0, 0, 0);
        if (grow < M) v = *(const float4*)(A + (size_t)grow * K + k0 + kc);
        if (i == 0) ar16_0 = v; else ar16_1 = v;
      }
    }
#pragma unroll
    for (int i = 0; i < BN / 64; ++i) {
      int chunk = tid + i * 256;
      int row = chunk >> 2, kc = (chunk & 3) * 8;
      float4 v = *(const float4*)(Bt + (size_t)(bn + row) * K + t * BK + kc);
      if (i == 0) br_0 = v; else br_1 = v;
    }
  };
  auto write_lds = [&](int buf) {
    if constexpr (AF32) {
#pragma unroll
      for (int i = 0; i < 4; ++i) {
        int chunk = tid + i * 256;
        int row = chunk >> 3, kc = (chunk & 7) * 4;
        float4 v = (i == 0) ? ar32_0 : (i == 1) ? ar32_1 : (i == 2) ? ar32_2 : ar32_3;
        __half2 h01 = __floats2half2_rn(v.x, v.y);
        __half2 h23 = __floats2half2_rn(v.z, v.w);
        uint2 u;
        u.x = *(unsigned*)&h01;
        u.y = *(unsigned*)&h23;
        *(uint2*)&As[buf][row][kc] = u;
      }
    } else {
#pragma unroll
      for (int i = 0; i < 2; ++i) {
        int chunk = tid + i * 256;
        int row = chunk >> 2, kc = (chunk & 3) * 8;
        *(float4*)&As[buf][row][kc] = (i == 0) ? ar16_0 : ar16_1;
      }
    }
#pragma unroll
    for (int i = 0; i < BN / 64; ++i) {
      int chunk = tid + i * 256;
      int row = chunk >> 2, kc = (chunk & 3) * 8;
      *(float4*)&Bs[buf][row][kc] = (i == 0) ? br_0 : br_1;
    }
  };
  auto compute = [&](int buf) {
    f16x8 af[4], bf[NFN];
#pragma unroll
    for (int mi = 0; mi < 4; ++mi)
      af[mi] = *(const f16x8*)&As[buf][wr * 64 + mi * 16 + r15][kgrp * 8];
#pragma unroll
    for (int ni = 0; ni < NFN; ++ni)
      bf[ni] = *(const f16x8*)&Bs[buf][wc * WN + ni * 16 + r15][kgrp * 8];
#pragma unroll
    for (int mi = 0; mi < 4; ++mi)
#pragma unroll
      for (int ni = 0; ni < NFN; ++ni)
        acc[mi][ni] = __builtin_amdgcn_mfma_f32_16x16x32_f16(af[mi], bf[ni], acc[mi][ni], 0, 0, 0);
  };

  const int nt = K / BK;
  issue_loads(0);
  write_lds(0);
  __syncthreads();
  for (int t = 0; t < nt; ++t) {
    int cur = t & 1;
    if (t + 1 < nt) issue_loads(t + 1);
    compute(cur);
    if (t + 1 < nt) {
      write_lds(cur ^ 1);
      __syncthreads();
    }
  }

  float asw[NFN], adw[NFN];
#pragma unroll
  for (int ni = 0; ni < NFN; ++ni) {
    int gcol = bn + wc * WN + ni * 16 + r15;
    asw[ni] = as_w[gcol];
    adw[ni] = ad_w[gcol];
  }
  const int hidx = (bn + wc * WN) >> 6;
#pragma unroll
  for (int mi = 0; mi < 4; ++mi) {
#pragma unroll
    for (int r = 0; r < 4; ++r) {
      int grow = bm + wr * 64 + mi * 16 + kgrp * 4 + r;
      bool valid = grow < M;
      float sdot = 0.f, ddot = 0.f;
#pragma unroll
      for (int ni = 0; ni < NFN; ++ni) {
        float v = acc[mi][ni][r];
        if (valid) {
          int gcol = bn + wc * WN + ni * 16 + r15;
          if constexpr (XF8) {
            unsigned pk = (unsigned)__builtin_amdgcn_cvt_pk_fp8_f32(v, v, 0, false);
            ((unsigned char*)Cv)[(size_t)grow * Nc + gcol] = (unsigned char)(pk & 0xff);
          } else {
            ((__half*)Cv)[(size_t)grow * Nc + gcol] = __float2half(v);
          }
        }
        sdot = fmaf(v, asw[ni], sdot);
        ddot = fmaf(v, adw[ni], ddot);
      }
#pragma unroll
      for (int o = 8; o >= 1; o >>= 1) {
        sdot += __shfl_xor(sdot, o);
        ddot += __shfl_xor(ddot, o);
      }
      if (valid && r15 == 0) {
        if constexpr (HS == 1) {
          atomicAdd(&asb[grow], sdot);
          atomicAdd(&adb[grow], ddot);
        } else {
          asb[(size_t)grow * HS + hidx] = sdot;
          adb[(size_t)grow * HS + hidx] = ddot;
        }
      }
    }
  }
}

// ---------------- fused segment-softmax + aggregation, heads=4 C=64, fp8 gather ----------------
// softmax WITHOUT max subtraction (shift-invariant; logits far below f32 exp overflow)
__global__ __launch_bounds__(256) void agg_heads4(
    const unsigned char* __restrict__ xp, const int2* __restrict__ se,
    const int* __restrict__ row_start, const float* __restrict__ asb,
    const float* __restrict__ adb, const float* __restrict__ ae,
    const float* __restrict__ bias, __half* __restrict__ out, int N) {
  __shared__ float sw[4][256];
  __shared__ int ssrc[4][64];  // pre-shifted row byte offsets (s << 8)
  int wave = threadIdx.x >> 6, lane = threadIdx.x & 63;
  int n = blockIdx.x * 4 + wave;
  if (n >= N) return;
  int beg = row_start[n], end = row_start[n + 1];
  int deg = end - beg;
  int hsel = lane >> 4;
  float4 adn = *(const float4*)(adb + (size_t)n * 4);
  float4 asn = *(const float4*)(asb + (size_t)n * 4);
  float invd = 1.f / fmaxf((float)deg, 1.f);
  float acc0 = 0, acc1 = 0, acc2 = 0, acc3 = 0;
  float den0 = 0, den1 = 0, den2 = 0, den3 = 0;
  float al0, al1, al2, al3, exl0, exl1, exl2, exl3;
  const int loff = lane << 2;  // 4 fp8 bytes / lane

  if (deg <= 64) {
    int j = beg + lane;
    bool act = j < end;
    int s = 0;
    float4 asv = make_float4(0, 0, 0, 0), aev = make_float4(0, 0, 0, 0);
    if (act) {
      s = se[j].x;
      asv = *(const float4*)(asb + (size_t)s * 4);
      aev = *(const float4*)(ae + (size_t)j * 4);
    }
    float ex0 = act ? __expf(lrelu(asv.x + adn.x + aev.x)) : 0.f;
    float ex1 = act ? __expf(lrelu(asv.y + adn.y + aev.y)) : 0.f;
    float ex2 = act ? __expf(lrelu(asv.z + adn.z + aev.z)) : 0.f;
    float ex3 = act ? __expf(lrelu(asv.w + adn.w + aev.w)) : 0.f;
    float aes0 = wred_sum(aev.x), aes1 = wred_sum(aev.y), aes2 = wred_sum(aev.z), aes3 = wred_sum(aev.w);
    al0 = lrelu(asn.x + adn.x + aes0 * invd);
    al1 = lrelu(asn.y + adn.y + aes1 * invd);
    al2 = lrelu(asn.z + adn.z + aes2 * invd);
    al3 = lrelu(asn.w + adn.w + aes3 * invd);
    exl0 = __expf(al0); exl1 = __expf(al1); exl2 = __expf(al2); exl3 = __expf(al3);
    den0 = wred_sum(ex0); den1 = wred_sum(ex1); den2 = wred_sum(ex2); den3 = wred_sum(ex3);
    *(float4*)&sw[wave][lane << 2] = make_float4(ex0, ex1, ex2, ex3);
    ssrc[wave][lane] = s << 8;
    asm volatile("" ::: "memory");
    int cnt = deg;
    int sj0 = ssrc[wave][0], sj1 = ssrc[wave][1], sj2 = ssrc[wave][2], sj3 = ssrc[wave][3];
    unsigned B0 = *(const unsigned*)(xp + sj0 + loff);
    unsigned B1 = *(const unsigned*)(xp + sj1 + loff);
    unsigned B2 = *(const unsigned*)(xp + sj2 + loff);
    unsigned B3 = *(const unsigned*)(xp + sj3 + loff);
    for (int t = 0; t < cnt; t += 4) {
      {
        float w = sw[wave][((t + 0) << 2) + hsel];
        f32x2v lo = __builtin_amdgcn_cvt_pk_f32_fp8((int)B0, false);
        f32x2v hi = __builtin_amdgcn_cvt_pk_f32_fp8((int)B0, true);
        acc0 = fmaf(w, lo[0], acc0); acc1 = fmaf(w, lo[1], acc1);
        acc2 = fmaf(w, hi[0], acc2); acc3 = fmaf(w, hi[1], acc3);
        int ns = ssrc[wave][(t + 4) & 63];
        B0 = *(const unsigned*)(xp + ns + loff);
      }
      {
        float w = sw[wave][((t + 1) << 2) + hsel];
        f32x2v lo = __builtin_amdgcn_cvt_pk_f32_fp8((int)B1, false);
        f32x2v hi = __builtin_amdgcn_cvt_pk_f32_fp8((int)B1, true);
        acc0 = fmaf(w, lo[0], acc0); acc1 = fmaf(w, lo[1], acc1);
        acc2 = fmaf(w, hi[0], acc2); acc3 = fmaf(w, hi[1], acc3);
        int ns = ssrc[wave][(t + 5) & 63];
        B1 = *(const unsigned*)(xp + ns + loff);
      }
      {
        float w = sw[wave][((t + 2) << 2) + hsel];
        f32x2v lo = __builtin_amdgcn_cvt_pk_f32_fp8((int)B2, false);
        f32x2v hi = __builtin_amdgcn_cvt_pk_f32_fp8((int)B2, true);
        acc0 = fmaf(w, lo[0], acc0); acc1 = fmaf(w, lo[1], acc1);
        acc2 = fmaf(w, hi[0], acc2); acc3 = fmaf(w, hi[1], acc3);
        int ns = ssrc[wave][(t + 6) & 63];
        B2 = *(const unsigned*)(xp + ns + loff);
      }
      {
        float w = sw[wave][((t + 3) << 2) + hsel];
        f32x2v lo = __builtin_amdgcn_cvt_pk_f32_fp8((int)B3, false);
        f32x2v hi = __builtin_amdgcn_cvt_pk_f32_fp8((int)B3, true);
        acc0 = fmaf(w, lo[0], acc0); acc1 = fmaf(w, lo[1], acc1);
        acc2 = fmaf(w, hi[0], acc2); acc3 = fmaf(w, hi[1], acc3);
        int ns = ssrc[wave][(t + 7) & 63];
        B3 = *(const unsigned*)(xp + ns + loff);
      }
    }
  } else {
    // pass A: only a_edge sums needed (no max pass)
    float aes0 = 0, aes1 = 0, aes2 = 0, aes3 = 0;
    for (int base = beg; base < end; base += 64) {
      int j = base + lane;
      if (j < end) {
        float4 aev = *(const float4*)(ae + (size_t)j * 4);
        aes0 += aev.x; aes1 += aev.y; aes2 += aev.z; aes3 += aev.w;
      }
    }
    aes0 = wred_sum(aes0); aes1 = wred_sum(aes1); aes2 = wred_sum(aes2); aes3 = wred_sum(aes3);
    al0 = lrelu(asn.x + adn.x + aes0 * invd);
    al1 = lrelu(asn.y + adn.y + aes1 * invd);
    al2 = lrelu(asn.z + adn.z + aes2 * invd);
    al3 = lrelu(asn.w + adn.w + aes3 * invd);
    exl0 = __expf(al0); exl1 = __expf(al1); exl2 = __expf(al2); exl3 = __expf(al3);
    for (int base = beg; base < end; base += 64) {
      int j = base + lane;
      float ex0 = 0, ex1 = 0, ex2 = 0, ex3 = 0;
      int s = 0;
      if (j < end) {
        s = se[j].x;
        float4 asv = *(const float4*)(asb + (size_t)s * 4);
        float4 aev = *(const float4*)(ae + (size_t)j * 4);
        ex0 = __expf(lrelu(asv.x + adn.x + aev.x));
        ex1 = __expf(lrelu(asv.y + adn.y + aev.y));
        ex2 = __expf(lrelu(asv.z + adn.z + aev.z));
        ex3 = __expf(lrelu(asv.w + adn.w + aev.w));
        den0 += ex0; den1 += ex1; den2 += ex2; den3 += ex3;
      }
      int cnt = min(64, end - base);
      for (int t = 0; t < cnt; ++t) {
        int sj = __shfl(s, t);
        float w0 = __shfl(ex0, t), w1 = __shfl(ex1, t), w2 = __shfl(ex2, t), w3 = __shfl(ex3, t);
        float w = hsel == 0 ? w0 : (hsel == 1 ? w1 : (hsel == 2 ? w2 : w3));
        unsigned u = *(const unsigned*)(xp + ((size_t)sj << 8) + loff);
        f32x2v lo = __builtin_amdgcn_cvt_pk_f32_fp8((int)u, false);
        f32x2v hi = __builtin_amdgcn_cvt_pk_f32_fp8((int)u, true);
        acc0 = fmaf(w, lo[0], acc0);
        acc1 = fmaf(w, lo[1], acc1);
        acc2 = fmaf(w, hi[0], acc2);
        acc3 = fmaf(w, hi[1], acc3);
      }
    }
    den0 = wred_sum(den0); den1 = wred_sum(den1); den2 = wred_sum(den2); den3 = wred_sum(den3);
  }

  den0 += exl0; den1 += exl1; den2 += exl2; den3 += exl3;
  float exh = hsel == 0 ? exl0 : (hsel == 1 ? exl1 : (hsel == 2 ? exl2 : exl3));
  {
    unsigned u = *(const unsigned*)(xp + ((size_t)n << 8) + loff);
    f32x2v lo = __builtin_amdgcn_cvt_pk_f32_fp8((int)u, false);
    f32x2v hi = __builtin_amdgcn_cvt_pk_f32_fp8((int)u, true);
    acc0 = fmaf(exh, lo[0], acc0);
    acc1 = fmaf(exh, lo[1], acc1);
    acc2 = fmaf(exh, hi[0], acc2);
    acc3 = fmaf(exh, hi[1], acc3);
  }
  float denh = hsel == 0 ? den0 : (hsel == 1 ? den1 : (hsel == 2 ? den2 : den3));
  float rden = 1.f / (denh + 1e-16f);
  float4 bv = *(const float4*)(bias + (lane << 2));
  __half2 o01 = __floats2half2_rn(fmaxf(acc0 * rden + bv.x, 0.f), fmaxf(acc1 * rden + bv.y, 0.f));
  __half2 o23 = __floats2half2_rn(fmaxf(acc2 * rden + bv.z, 0.f), fmaxf(acc3 * rden + bv.w, 0.f));
  uint2 u;
  u.x = *(unsigned*)&o01;
  u.y = *(unsigned*)&o23;
  *(uint2*)(out + (size_t)n * 256 + (lane << 2)) = u;
}

// ---------------- layer2 (heads=1, fp16 table) + final linear + sigmoid, fused ----------------
__global__ __launch_bounds__(256) void agg1_final(
    const __half* __restrict__ xp, const int2* __restrict__ se,
    const int* __restrict__ row_start, const float* __restrict__ asb,
    const float* __restrict__ adb, const float* __restrict__ ae,
    const float* __restrict__ b2, const float* __restrict__ lin_w,
    const float* __restrict__ lin_b, float* __restrict__ out, int N) {
  __shared__ float sw1[4][64];
  __shared__ int ssrc1[4][64];
  int wave = threadIdx.x >> 6, lane = threadIdx.x & 63;
  int n = blockIdx.x * 4 + wave;
  if (n >= N) return;
  int beg = row_start[n], end = row_start[n + 1];
  int deg = end - beg;
  float adn = adb[n], asn = asb[n];
  float invd = 1.f / fmaxf((float)deg, 1.f);
  float al, exl, acc = 0, den = 0;

  if (deg <= 64) {
    int j = beg + lane;
    bool act = j < end;
    int s = 0;
    float aev = 0, asvs = 0;
    if (act) { s = se[j].x; aev = ae[j]; asvs = asb[s]; }
    float ex = act ? __expf(lrelu(asvs + adn + aev)) : 0.f;
    float aes = wred_sum(aev);
    al = lrelu(asn + adn + aes * invd);
    exl = __expf(al);
    den = wred_sum(ex);
    sw1[wave][lane] = ex;
    ssrc1[wave][lane] = s;
    asm volatile("" ::: "memory");
    int cnt = deg;
    int sj0 = ssrc1[wave][0], sj1 = ssrc1[wave][1], sj2 = ssrc1[wave][2], sj3 = ssrc1[wave][3];
    __half H0 = xp[((size_t)sj0 << 6) + lane];
    __half H1 = xp[((size_t)sj1 << 6) + lane];
    __half H2 = xp[((size_t)sj2 << 6) + lane];
    __half H3 = xp[((size_t)sj3 << 6) + lane];
    for (int t = 0; t < cnt; t += 4) {
      {
        float w = sw1[wave][t + 0];
        acc = fmaf(w, __half2float(H0), acc);
        int ns = ssrc1[wave][(t + 4) & 63];
        H0 = xp[((size_t)ns << 6) + lane];
      }
      {
        float w = sw1[wave][t + 1];
        acc = fmaf(w, __half2float(H1), acc);
        int ns = ssrc1[wave][(t + 5) & 63];
        H1 = xp[((size_t)ns << 6) + lane];
      }
      {
        float w = sw1[wave][t + 2];
        acc = fmaf(w, __half2float(H2), acc);
        int ns = ssrc1[wave][(t + 6) & 63];
        H2 = xp[((size_t)ns << 6) + lane];
      }
      {
        float w = sw1[wave][t + 3];
        acc = fmaf(w, __half2float(H3), acc);
        int ns = ssrc1[wave][(t + 7) & 63];
        H3 = xp[((size_t)ns << 6) + lane];
      }
    }
  } else {
    float aes = 0;
    for (int base = beg; base < end; base += 64) {
      int j = base + lane;
      if (j < end) aes += ae[j];
    }
    aes = wred_sum(aes);
    al = lrelu(asn + adn + aes * invd);
    exl = __expf(al);
    for (int base = beg; base < end; base += 64) {
      int j = base + lane;
      float ex = 0;
      int s = 0;
      if (j < end) {
        s = se[j].x;
        ex = __expf(lrelu(asb[s] + adn + ae[j]));
        den += ex;
      }
      int cnt = min(64, end - base);
      for (int t = 0; t < cnt; ++t) {
        int sj = __shfl(s, t);
        float w = __shfl(ex, t);
        acc = fmaf(w, __half2float(xp[((size_t)sj << 6) + lane]), acc);
      }
    }
    den = wred_sum(den);
  }

  den += exl;
  acc = fmaf(exl, __half2float(xp[((size_t)n << 6) + lane]), acc);
  float h = fmaxf(acc / (den + 1e-16f) + b2[lane], 0.f);
  float p = wred_sum(h * lin_w[lane]);
  if (lane == 0) out[n] = 1.f / (1.f + __expf(-(p + lin_b[0])));
}

// ---------------- host glue ----------------
extern "C" void kernel_launch(void* const* d_in, const int* in_sizes, int n_in,
                              void* d_out, int out_size, void* d_ws, size_t ws_size,
                              hipStream_t stream) {
  const float* x    = (const float*)d_in[0];
  const int*   ei   = (const int*)d_in[1];
  const float* ea   = (const float*)d_in[2];
  const float* W0   = (const float*)d_in[3];
  const float* as0w = (const float*)d_in[4];
  const float* ad0w = (const float*)d_in[5];
  const float* We0  = (const float*)d_in[6];
  const float* ae0w = (const float*)d_in[7];
  const float* b0   = (const float*)d_in[8];
  const float* W1   = (const float*)d_in[9];
  const float* as1w = (const float*)d_in[10];
  const float* ad1w = (const float*)d_in[11];
  const float* We1  = (const float*)d_in[12];
  const float* ae1w = (const float*)d_in[13];
  const float* b1   = (const float*)d_in[14];
  const float* W2   = (const float*)d_in[15];
  const float* as2w = (const float*)d_in[16];
  const float* ad2w = (const float*)d_in[17];
  const float* We2  = (const float*)d_in[18];
  const float* ae2w = (const float*)d_in[19];
  const float* b2   = (const float*)d_in[20];
  const float* linw = (const float*)d_in[21];
  const float* linb = (const float*)d_in[22];

  const int N = in_sizes[0] / 128;
  const int E = in_sizes[1] / 2;
  const int* src = ei;
  const int* dst = ei + E;

  char* p = (char*)d_ws;
  auto alloc = [&](size_t bytes) {
    char* r = p;
    p += (bytes + 255) & ~size_t(255);
    return r;
  };
  __half*        bufAh = (__half*)alloc((size_t)N * 256 * 2);
  unsigned char* xp8   = (unsigned char*)alloc((size_t)N * 256);  // fp8 gather table L0/L1
  __half*        xph2  = (__half*)alloc((size_t)N * 64 * 2);      // fp16 table L2
  __half*        W0t   = (__half*)alloc((size_t)256 * 128 * 2);
  __half*        W1t   = (__half*)alloc((size_t)256 * 256 * 2);
  __half*        W2t   = (__half*)alloc((size_t)64 * 256 * 2);
  float*         asb0  = (float*)alloc((size_t)N * 4 * 4);
  float*         adb0  = (float*)alloc((size_t)N * 4 * 4);
  float*         asb1  = (float*)alloc((size_t)N * 4 * 4);
  float*         adb1  = (float*)alloc((size_t)N * 4 * 4);
  // contiguous zero region: deg, asb2, adb2
  char*   zbase      = p;
  int*    deg        = (int*)alloc((size_t)N * 4);
  float*  asb2       = (float*)alloc((size_t)N * 4);
  float*  adb2       = (float*)alloc((size_t)N * 4);
  size_t  zspan      = (size_t)(p - zbase);
  int*    rank       = (int*)alloc((size_t)E * 4);
  int2*   se         = (int2*)alloc((size_t)E * 8);
  float*  ae0s       = (float*)alloc((size_t)E * 4 * 4);
  float*  ae1s       = (float*)alloc((size_t)E * 4 * 4);
  float*  ae2s       = (float*)alloc((size_t)E * 4);
  int*    row_start  = (int*)alloc((size_t)(N + 1) * 4);
  int*    bsum       = (int*)alloc((size_t)256 * 4);
  float*  wv         = (float*)alloc(144 * 4);

  int nb = (N + 255) / 256;
  int eb = (E + 255) / 256;
  hipMemsetAsync(zbase, 0, zspan, stream);
  count_rank<<<eb, 256, 0, stream>>>(dst, deg, rank, E);
  scan_part<<<nb, 256, 0, stream>>>(deg, bsum, N);
  scan_final<<<nb, 256, 0, stream>>>(deg, bsum, row_start, N, nb);
  scatter_edges<<<eb, 256, 0, stream>>>(src, dst, row_start, rank, se, E);
  prep_weights<<<449, 256, 0, stream>>>(W0, W0t, W1, W1t, W2, W2t,
                                        We0, ae0w, We1, ae1w, We2, ae2w, wv);
  edge_ae<<<eb, 256, 0, stream>>>(ea, se, wv, ae0s, ae1s, ae2s, E);

  int gm = (N + 127) / 128;
  int nwb = (N + 3) / 4;
  // layer 0: A = x (f32, converted during staging); C -> fp8 table; fused asad
  gemm_f16mfma<128, true, 4, true><<<dim3(gm, 2), 256, 0, stream>>>(
      x, W0t, xp8, as0w, ad0w, asb0, adb0, N, 128, 256);
  agg_heads4<<<nwb, 256, 0, stream>>>(xp8, se, row_start, asb0, adb0, ae0s, b0, bufAh, N);
  // layer 1
  gemm_f16mfma<128, false, 4, true><<<dim3(gm, 2), 256, 0, stream>>>(
      bufAh, W1t, xp8, as1w, ad1w, asb1, adb1, N, 256, 256);
  agg_heads4<<<nwb, 256, 0, stream>>>(xp8, se, row_start, asb1, adb1, ae1s, b1, bufAh, N);
  // layer 2 (fp16 table) + final linear + sigmoid
  gemm_f16mfma<64, false, 1, false><<<dim3(gm, 1), 256, 0, stream>>>(
      bufAh, W2t, xph2, as2w, ad2w, asb2, adb2, N, 256, 64);
  agg1_final<<<nwb, 256, 0, stream>>>(xph2, se, row_start, asb2, adb2, ae2s, b2, linw, linb,
                                      (float*)d_out, N);
}